// Round 21
// baseline (331.651 us; speedup 1.0000x reference)
//
#include <hip/hip_runtime.h>

#define Bb 8
#define Nn 2048
#define Dd 512

#define KV 32            // keys per tile/image
#define NT 64            // images per batch
#define PPS 40           // sP row stride (u16 elements)

// fallback (no ws): R10 structure
#define KVF 64
#define NTF (Nn / KVF)
#define PPF 72

typedef __attribute__((ext_vector_type(8))) short bf8;
typedef __attribute__((ext_vector_type(4))) float f4;
struct __align__(16) U8 { unsigned short s[8]; };
struct __align__(8) US4 { unsigned short s[4]; };

__device__ __forceinline__ unsigned short f2bf(float f) {
  union { float f; unsigned u; } v; v.f = f;
  unsigned r = v.u + 0x7fffu + ((v.u >> 16) & 1u);
  return (unsigned short)(r >> 16);
}
__device__ __forceinline__ float bf2f(unsigned short h) {
  union { unsigned u; float f; } v; v.u = ((unsigned)h) << 16; return v.f;
}

// async global->LDS, 16B per lane; LDS dest = wave-uniform base + lane*16
__device__ __forceinline__ void gload_lds16(const unsigned short* g, unsigned short* l) {
  __builtin_amdgcn_global_load_lds(
      (const __attribute__((address_space(1))) void*)g,
      (__attribute__((address_space(3))) void*)l, 16, 0, 0);
}

// ---------------------------------------------------------------------------
// Build per-(b,tile) images in ws, once.  Image = [K 16384 | Vt 16384] u16.
//   K : key*512 + ((c ^ (key&7))<<3), c = d>>3        (LDS-swizzled row-major)
//   Vt: 16384 + d*32 + ((g ^ ((d>>1)&3))<<3), g = key>>3  (transpose)
// (identical to the 178 us R19 kernel)
// ---------------------------------------------------------------------------
__global__ __launch_bounds__(256)
void build_images(const float* __restrict__ X, unsigned short* __restrict__ W) {
  __shared__ float sT[KV * Dd];  // 64 KB
  const int t = blockIdx.x, b = blockIdx.y, tid = threadIdx.x;
  const float* src = X + ((size_t)b * Nn + t * KV) * Dd;
#pragma unroll
  for (int i = 0; i < 16; ++i) {
    int idx = i * 256 + tid;
    *(float4*)(sT + idx * 4) = *(const float4*)(src + idx * 4);
  }
  __syncthreads();
  unsigned short* img = W + ((size_t)(b * NT + t) << 15);
#pragma unroll
  for (int i = 0; i < 8; ++i) {
    int idx = i * 256 + tid;
    int key = idx >> 6, c = idx & 63;
    const float* p = sT + key * Dd + c * 8;
    U8 v;
#pragma unroll
    for (int j = 0; j < 8; ++j) v.s[j] = f2bf(p[j]);
    *(U8*)(img + key * 512 + ((c ^ (key & 7)) << 3)) = v;
  }
#pragma unroll
  for (int i = 0; i < 8; ++i) {
    int idx = i * 256 + tid;
    int d = idx >> 2, g = idx & 3;
    U8 v;
#pragma unroll
    for (int e = 0; e < 8; ++e) v.s[e] = f2bf(sT[(g * 8 + e) * Dd + d]);
    *(U8*)(img + 16384 + d * 32 + ((g ^ ((d >> 1) & 3)) << 3)) = v;
  }
}

// ---------------------------------------------------------------------------
// D-half-split attention (R19 structure, 178 us) + two validated tweaks:
//  (1) no-max softmax: p = exp((lo+hi)*rs), rs = scale*mask (masked -> p=1
//      exact, uniform collapse; scores bounded ~29 so exp is f32-safe);
//      row-sum via ones-MFMA accumulated across tiles (both validated in R20,
//      absmax bit-identical 0.015625). Removes 32 shfls + rescale per tile.
//  (2) s_setprio(1) around the MFMA clusters (T5; 2 blocks/SIMD interleave).
// Everything else identical: 256 thr = 4 waves = 2qg x 2dh; K image in LDS
// via global_load_lds; V from L2; sSx bf16 partial exchange; 2 barriers/tile.
// ---------------------------------------------------------------------------
__global__ __launch_bounds__(256, 2)
void attn_dh(const unsigned short* __restrict__ W, const int* __restrict__ mask,
             float* __restrict__ out) {
  __shared__ unsigned short sK[16384];   // 32 KB
  __shared__ US4 sSx[2][2][2][64];       // 4 KB: [qg][dh][cc][slot]
  __shared__ unsigned short sP[2][16 * PPS];  // 2.5 KB

  const int tid  = threadIdx.x;
  const int wave = tid >> 6;
  const int qg = wave >> 1, dh = wave & 1;
  const int lane = tid & 63;
  const int lg = lane >> 4, ll = lane & 15;
  const int slot = lg * 16 + ll;
  const int bid = blockIdx.x;
  const int b = bid & 7;                      // XCD-batch affinity
  const int qb = bid >> 3;                    // 0..63
  const int q0 = qb * 32 + qg * 16;
  const int bN = b * NT;
  const float scale = 0.044194173824159216f;  // 1/sqrt(512)

  // Q fragments for this wave's d-half (from K-images; same addr math as K)
  bf8 qf[8];
  {
    int qrow = q0 + ll;
    const unsigned short* qimg = W + ((size_t)(bN + (qrow >> 5)) << 15);
    int qk = qrow & 31;
#pragma unroll
    for (int ch = 0; ch < 8; ++ch) {
      int c = dh * 32 + ch * 4 + lg;
      qf[ch] = *(const bf8*)(qimg + qk * 512 + ((c ^ (qk & 7)) << 3));
    }
  }

  // row scale with mask folded: masked -> rs = 0 -> e = 0 -> p = 1 exactly
  float rs[4];
#pragma unroll
  for (int r = 0; r < 4; ++r)
    rs[r] = scale * (float)mask[b * Nn + q0 + lg * 4 + r];

  bf8 ones;
#pragma unroll
  for (int i = 0; i < 8; ++i) ones[i] = (short)0x3F80;  // bf16 1.0

  f4 o[16];
  f4 lacc = (f4){0.f, 0.f, 0.f, 0.f};
#pragma unroll
  for (int ct = 0; ct < 16; ++ct) o[ct] = (f4){0.f, 0.f, 0.f, 0.f};

  // prologue: stage K tile 0 via async global->LDS (8 x 1KB per wave)
  {
    const unsigned short* img0 = W + ((size_t)bN << 15);
#pragma unroll
    for (int i = 0; i < 8; ++i) {
      int chunk = i * 4 + wave;  // 0..31, 1 KB each
      gload_lds16(img0 + chunk * 512 + lane * 8, sK + chunk * 512);
    }
  }
  __syncthreads();

  for (int t = 0; t < NT; ++t) {
    // ---- QK^T partial over d-half: 16 MFMAs ----
    f4 s2[2];
    s2[0] = (f4){0.f, 0.f, 0.f, 0.f};
    s2[1] = (f4){0.f, 0.f, 0.f, 0.f};
    __builtin_amdgcn_s_setprio(1);
#pragma unroll
    for (int ch = 0; ch < 8; ++ch) {
#pragma unroll
      for (int cc = 0; cc < 2; ++cc) {
        int key = cc * 16 + ll;
        int c = dh * 32 + ch * 4 + lg;
        bf8 kf = *(const bf8*)(sK + key * 512 + ((c ^ (key & 7)) << 3));
        s2[cc] = __builtin_amdgcn_mfma_f32_16x16x32_bf16(qf[ch], kf, s2[cc], 0, 0, 0);
      }
    }
    __builtin_amdgcn_s_setprio(0);
    // publish partials (bf16x4; separate buffer -> no extra barrier)
#pragma unroll
    for (int cc = 0; cc < 2; ++cc) {
      US4 w;
#pragma unroll
      for (int r = 0; r < 4; ++r) w.s[r] = f2bf(s2[cc][r]);
      sSx[qg][dh][cc][slot] = w;
    }
    __syncthreads();  // barA: sK reads done, partials visible

    // issue next K tile (async, lands by barB's drain)
    if (t + 1 < NT) {
      const unsigned short* gKn = W + ((size_t)(bN + t + 1) << 15);
#pragma unroll
      for (int i = 0; i < 8; ++i) {
        int chunk = i * 4 + wave;
        gload_lds16(gKn + chunk * 512 + lane * 8, sK + chunk * 512);
      }
    }

    // ---- no-max softmax: e = (lo+hi)*rs, p = exp(e); P -> sP ----
#pragma unroll
    for (int cc = 0; cc < 2; ++cc) {
      US4 lo = sSx[qg][0][cc][slot];
      US4 hi = sSx[qg][1][cc][slot];
#pragma unroll
      for (int r = 0; r < 4; ++r) {
        float e = (bf2f(lo.s[r]) + bf2f(hi.s[r])) * rs[r];
        sP[qg][(lg * 4 + r) * PPS + cc * 16 + ll] = f2bf(__expf(e));
      }
    }
    // af read: this wave wrote the full 16x32 P itself -> same-wave ordered
    bf8 af = *(const bf8*)(sP[qg] + ll * PPS + lg * 8);

    // row-sum via ones-MFMA (accumulates across tiles; 2048 exact if masked)
    lacc = __builtin_amdgcn_mfma_f32_16x16x32_bf16(af, ones, lacc, 0, 0, 0);

    // ---- PV: this wave's d-half of V straight from L2 ----
    const unsigned short* gV = W + ((size_t)(bN + t) << 15) + 16384;
    __builtin_amdgcn_s_setprio(1);
#pragma unroll
    for (int g2 = 0; g2 < 8; ++g2) {
      bf8 va0, va1;
      {
        int d0 = dh * 256 + (g2 * 2) * 16 + ll;
        int d1 = dh * 256 + (g2 * 2 + 1) * 16 + ll;
        va0 = *(const bf8*)(gV + d0 * 32 + ((lg ^ ((d0 >> 1) & 3)) << 3));
        va1 = *(const bf8*)(gV + d1 * 32 + ((lg ^ ((d1 >> 1) & 3)) << 3));
      }
      o[g2 * 2]     = __builtin_amdgcn_mfma_f32_16x16x32_bf16(af, va0, o[g2 * 2], 0, 0, 0);
      o[g2 * 2 + 1] = __builtin_amdgcn_mfma_f32_16x16x32_bf16(af, va1, o[g2 * 2 + 1], 0, 0, 0);
    }
    __builtin_amdgcn_s_setprio(0);
    __syncthreads();  // barB: K loads drained; sSx/sP reads settled
  }

  // ---- epilogue: normalize by MFMA row-sums, store 16q x 256d ----
  float inv[4];
#pragma unroll
  for (int r = 0; r < 4; ++r) inv[r] = 1.0f / lacc[r];
#pragma unroll
  for (int ct = 0; ct < 16; ++ct)
#pragma unroll
    for (int r = 0; r < 4; ++r) {
      size_t row = (size_t)b * Nn + q0 + lg * 4 + r;
      out[row * Dd + dh * 256 + ct * 16 + ll] = o[ct][r] * inv[r];
    }
}

// ---------------------------------------------------------------------------
// Fallback (no usable ws): R10 structure, KV=64, in-kernel convert.
// ---------------------------------------------------------------------------
__global__ __launch_bounds__(256, 1)
void attn_fb(const float* __restrict__ Xf, const int* __restrict__ mask,
             float* __restrict__ out) {
  __shared__ unsigned short sKf[KVF * Dd];
  __shared__ unsigned short sVt[Dd * KVF];
  __shared__ unsigned short sPf[4][16 * PPF];

  const int tid  = threadIdx.x;
  const int wave = tid >> 6, lane = tid & 63;
  const int lg = lane >> 4, ll = lane & 15;
  const int b  = blockIdx.y;
  const int q0 = blockIdx.x * 64 + wave * 16;

  bf8 qf[16];
  {
    const size_t qoff = ((size_t)b * Nn + q0 + ll) * Dd;
#pragma unroll
    for (int ch = 0; ch < 16; ++ch) {
      int doff = ch * 32 + lg * 8;
      float4 a = *(const float4*)(Xf + qoff + doff);
      float4 c = *(const float4*)(Xf + qoff + doff + 4);
      bf8 tt;
      tt[0] = (short)f2bf(a.x); tt[1] = (short)f2bf(a.y);
      tt[2] = (short)f2bf(a.z); tt[3] = (short)f2bf(a.w);
      tt[4] = (short)f2bf(c.x); tt[5] = (short)f2bf(c.y);
      tt[6] = (short)f2bf(c.z); tt[7] = (short)f2bf(c.w);
      qf[ch] = tt;
    }
  }
  float bias[4];
#pragma unroll
  for (int r = 0; r < 4; ++r)
    bias[r] = (1.0f - (float)mask[b * Nn + q0 + lg * 4 + r]) * 1e9f;
  float m[4], lsum[4];
  f4 o[32];
#pragma unroll
  for (int r = 0; r < 4; ++r) { m[r] = -1e30f; lsum[r] = 0.0f; }
#pragma unroll
  for (int ct = 0; ct < 32; ++ct) o[ct] = (f4){0.f, 0.f, 0.f, 0.f};
  const float scale = 0.044194173824159216f;

  for (int t = 0; t < NTF; ++t) {
    __syncthreads();
    const size_t base = ((size_t)b * Nn + t * KVF) * Dd;
#pragma unroll
    for (int it = 0; it < 16; ++it) {
      int idx = it * 256 + tid;
      int key = idx >> 6, c = idx & 63;
      const float* sp = Xf + base + key * Dd + c * 8;
      float4 a = *(const float4*)(sp);
      float4 d2 = *(const float4*)(sp + 4);
      U8 v;
      v.s[0] = f2bf(a.x); v.s[1] = f2bf(a.y); v.s[2] = f2bf(a.z); v.s[3] = f2bf(a.w);
      v.s[4] = f2bf(d2.x); v.s[5] = f2bf(d2.y); v.s[6] = f2bf(d2.z); v.s[7] = f2bf(d2.w);
      *(U8*)(sKf + key * 512 + ((c ^ (key & 7)) << 3)) = v;
      int ko = key >> 3, k7 = key & 7;
#pragma unroll
      for (int j = 0; j < 8; ++j) {
        int dd = c * 8 + j;
        sVt[dd * 64 + ((ko ^ j ^ (c & 7)) << 3) + k7] = v.s[j];
      }
    }
    __syncthreads();

    f4 s[4];
#pragma unroll
    for (int cc = 0; cc < 4; ++cc) s[cc] = (f4){0.f, 0.f, 0.f, 0.f};
#pragma unroll
    for (int ch = 0; ch < 16; ++ch)
#pragma unroll
      for (int cc = 0; cc < 4; ++cc) {
        int key = cc * 16 + ll;
        bf8 kf = *(const bf8*)(sKf + key * 512 + (((ch * 4 + lg) ^ (key & 7)) << 3));
        s[cc] = __builtin_amdgcn_mfma_f32_16x16x32_bf16(qf[ch], kf, s[cc], 0, 0, 0);
      }

    float e[4][4];
#pragma unroll
    for (int cc = 0; cc < 4; ++cc)
#pragma unroll
      for (int r = 0; r < 4; ++r) e[cc][r] = s[cc][r] * scale - bias[r];
    float tm[4];
#pragma unroll
    for (int r = 0; r < 4; ++r)
      tm[r] = fmaxf(fmaxf(e[0][r], e[1][r]), fmaxf(e[2][r], e[3][r]));
#pragma unroll
    for (int off = 1; off < 16; off <<= 1)
#pragma unroll
      for (int r = 0; r < 4; ++r) tm[r] = fmaxf(tm[r], __shfl_xor(tm[r], off));
    float mn[4]; bool change = false;
#pragma unroll
    for (int r = 0; r < 4; ++r) { mn[r] = fmaxf(m[r], tm[r]); change = change || (mn[r] > m[r]); }
    if (__any(change)) {
#pragma unroll
      for (int r = 0; r < 4; ++r) {
        float al = __expf(m[r] - mn[r]);
        lsum[r] *= al; m[r] = mn[r];
#pragma unroll
        for (int ct = 0; ct < 32; ++ct) o[ct][r] *= al;
      }
    }
    float ts[4] = {0.f, 0.f, 0.f, 0.f};
    unsigned short pb[4][4];
#pragma unroll
    for (int cc = 0; cc < 4; ++cc)
#pragma unroll
      for (int r = 0; r < 4; ++r) {
        float p = __expf(e[cc][r] - m[r]);
        ts[r] += p; pb[cc][r] = f2bf(p);
      }
#pragma unroll
    for (int off = 1; off < 16; off <<= 1)
#pragma unroll
      for (int r = 0; r < 4; ++r) ts[r] += __shfl_xor(ts[r], off);
#pragma unroll
    for (int r = 0; r < 4; ++r) lsum[r] += ts[r];

    unsigned short* Pw = sPf[wave];
#pragma unroll
    for (int cc = 0; cc < 4; ++cc)
#pragma unroll
      for (int r = 0; r < 4; ++r)
        Pw[(lg * 4 + r) * PPF + cc * 16 + ll] = pb[cc][r];
#pragma unroll
    for (int kc = 0; kc < 2; ++kc) {
      bf8 af = *(const bf8*)(Pw + ll * PPF + kc * 32 + lg * 8);
#pragma unroll
      for (int ct = 0; ct < 32; ++ct) {
        int d = ct * 16 + ll;
        bf8 vf = *(const bf8*)(sVt + d * 64 + (((kc * 4 + lg) ^ (d & 7) ^ ((d >> 3) & 7)) << 3));
        o[ct] = __builtin_amdgcn_mfma_f32_16x16x32_bf16(af, vf, o[ct], 0, 0, 0);
      }
    }
  }
  float inv[4];
#pragma unroll
  for (int r = 0; r < 4; ++r) inv[r] = 1.0f / lsum[r];
#pragma unroll
  for (int ct = 0; ct < 32; ++ct)
#pragma unroll
    for (int r = 0; r < 4; ++r) {
      size_t row = (size_t)b * Nn + q0 + lg * 4 + r;
      out[row * Dd + ct * 16 + ll] = o[ct][r] * inv[r];
    }
}

extern "C" void kernel_launch(void* const* d_in, const int* in_sizes, int n_in,
                              void* d_out, int out_size, void* d_ws, size_t ws_size,
                              hipStream_t stream) {
  (void)in_sizes; (void)n_in; (void)out_size;
  const float* X  = (const float*)d_in[0];
  const int* mask = (const int*)d_in[1];
  float* out = (float*)d_out;

  const size_t szImg = (size_t)Bb * NT * 65536;  // 32 MiB of bf16 images
  if (ws_size >= szImg) {
    unsigned short* W = (unsigned short*)d_ws;
    build_images<<<dim3(NT, Bb), 256, 0, stream>>>(X, W);
    attn_dh<<<512, 256, 0, stream>>>(W, mask, out);
  } else {
    attn_fb<<<dim3(Nn / 64, Bb), 256, 0, stream>>>(X, mask, out);
  }
}

// Round 22
// 178.870 us; speedup vs baseline: 1.8541x; 1.8541x over previous
//
#include <hip/hip_runtime.h>

#define Bb 8
#define Nn 2048
#define Dd 512

#define KV 32            // keys per tile/image
#define NT 64            // images per batch
#define PPS 40           // sP row stride (u16 elements)

// fallback (no ws): R10 structure
#define KVF 64
#define NTF (Nn / KVF)
#define PPF 72

typedef __attribute__((ext_vector_type(8))) short bf8;
typedef __attribute__((ext_vector_type(4))) float f4;
struct __align__(16) U8 { unsigned short s[8]; };
struct __align__(8) US4 { unsigned short s[4]; };

__device__ __forceinline__ unsigned short f2bf(float f) {
  union { float f; unsigned u; } v; v.f = f;
  unsigned r = v.u + 0x7fffu + ((v.u >> 16) & 1u);
  return (unsigned short)(r >> 16);
}
__device__ __forceinline__ float bf2f(unsigned short h) {
  union { unsigned u; float f; } v; v.u = ((unsigned)h) << 16; return v.f;
}

// async global->LDS, 16B per lane; LDS dest = wave-uniform base + lane*16
__device__ __forceinline__ void gload_lds16(const unsigned short* g, unsigned short* l) {
  __builtin_amdgcn_global_load_lds(
      (const __attribute__((address_space(1))) void*)g,
      (__attribute__((address_space(3))) void*)l, 16, 0, 0);
}

// ---------------------------------------------------------------------------
// Build per-(b,tile) images in ws, once.  Image = [K 16384 | Vt 16384] u16.
//   K : key*512 + ((c ^ (key&7))<<3), c = d>>3        (LDS-swizzled row-major)
//   Vt: 16384 + d*32 + ((g ^ ((d>>1)&3))<<3), g = key>>3  (transpose)
// (identical to the 178 us R19 kernel)
// ---------------------------------------------------------------------------
__global__ __launch_bounds__(256)
void build_images(const float* __restrict__ X, unsigned short* __restrict__ W) {
  __shared__ float sT[KV * Dd];  // 64 KB
  const int t = blockIdx.x, b = blockIdx.y, tid = threadIdx.x;
  const float* src = X + ((size_t)b * Nn + t * KV) * Dd;
#pragma unroll
  for (int i = 0; i < 16; ++i) {
    int idx = i * 256 + tid;
    *(float4*)(sT + idx * 4) = *(const float4*)(src + idx * 4);
  }
  __syncthreads();
  unsigned short* img = W + ((size_t)(b * NT + t) << 15);
#pragma unroll
  for (int i = 0; i < 8; ++i) {
    int idx = i * 256 + tid;
    int key = idx >> 6, c = idx & 63;
    const float* p = sT + key * Dd + c * 8;
    U8 v;
#pragma unroll
    for (int j = 0; j < 8; ++j) v.s[j] = f2bf(p[j]);
    *(U8*)(img + key * 512 + ((c ^ (key & 7)) << 3)) = v;
  }
#pragma unroll
  for (int i = 0; i < 8; ++i) {
    int idx = i * 256 + tid;
    int d = idx >> 2, g = idx & 3;
    U8 v;
#pragma unroll
    for (int e = 0; e < 8; ++e) v.s[e] = f2bf(sT[(g * 8 + e) * Dd + d]);
    *(U8*)(img + 16384 + d * 32 + ((g ^ ((d >> 1) & 3)) << 3)) = v;
  }
}

// ---------------------------------------------------------------------------
// Single-block double-buffered attention. 512 thr = 8 waves = 4 qg x 2 dh.
// Wave (qg,dh): 16 q-rows (q0 = qb*64 + qg*16), d-half [dh*256, +256).
// Per-wave state ~112 VGPR <= the 128 cap of 512-thr blocks (the D-half split
// is what makes a 512-thr block viable; R12/13 needed ~200 and spilled).
// Grid 256 = 1 block/CU = 2 waves/SIMD.  LDS: 2 x 64 KB [K|Vt] image buffers
// (double-buffered; V now read from LDS, killing PV's serial ~300cy L2 loads)
// + sSx 8 KB + sP 5 KB = 144 KB static.
// Tile: QK^T(buf[cur].K) -> sSx -> barA -> prefetch tile t+1 into buf[cur^1]
// (8 gload_lds16/wave; covered by softmax+PV) -> shfl softmax (R19 verbatim)
// -> PV(buf[cur].Vt, conflict-free swizzle) -> barB (drain) -> swap.
// 2 barriers/tile. No setprio (R21: regression).
// ---------------------------------------------------------------------------
__global__ __launch_bounds__(512, 1)
void attn_db(const unsigned short* __restrict__ W, const int* __restrict__ mask,
             float* __restrict__ out) {
  __shared__ unsigned short sBuf[2][32768];   // 2 x 64 KB [K 16384 | Vt 16384]
  __shared__ US4 sSx[4][2][2][64];            // 8 KB [qg][dh][cc][slot]
  __shared__ unsigned short sP[4][16 * PPS];  // 5 KB

  const int tid  = threadIdx.x;
  const int wave = tid >> 6;
  const int qg = wave >> 1, dh = wave & 1;
  const int lane = tid & 63;
  const int lg = lane >> 4, ll = lane & 15;
  const int slot = lg * 16 + ll;
  const int bid = blockIdx.x;
  const int b = bid & 7;                      // XCD-batch affinity
  const int qb = bid >> 3;                    // 0..31
  const int q0 = qb * 64 + qg * 16;
  const int bN = b * NT;
  const float scale = 0.044194173824159216f;  // 1/sqrt(512)

  // Q fragments for this wave's d-half (from K-images; same addr math as K)
  bf8 qf[8];
  {
    int qrow = q0 + ll;
    const unsigned short* qimg = W + ((size_t)(bN + (qrow >> 5)) << 15);
    int qk = qrow & 31;
#pragma unroll
    for (int ch = 0; ch < 8; ++ch) {
      int c = dh * 32 + ch * 4 + lg;
      qf[ch] = *(const bf8*)(qimg + qk * 512 + ((c ^ (qk & 7)) << 3));
    }
  }

  float bias[4];
#pragma unroll
  for (int r = 0; r < 4; ++r)
    bias[r] = (1.0f - (float)mask[b * Nn + q0 + lg * 4 + r]) * 1e9f;

  float m[4], lsum[4];
  f4 o[16];
#pragma unroll
  for (int r = 0; r < 4; ++r) { m[r] = -1e30f; lsum[r] = 0.0f; }
#pragma unroll
  for (int ct = 0; ct < 16; ++ct) o[ct] = (f4){0.f, 0.f, 0.f, 0.f};

  // prologue: stage full image of tile 0 (64 chunks of 1 KB; 8 per wave)
  {
    const unsigned short* img0 = W + ((size_t)bN << 15);
#pragma unroll
    for (int i = 0; i < 8; ++i) {
      int chunk = i * 8 + wave;  // 0..63
      gload_lds16(img0 + chunk * 512 + lane * 8, sBuf[0] + chunk * 512);
    }
  }
  __syncthreads();

  int cur = 0;
  for (int t = 0; t < NT; ++t) {
    const unsigned short* sK = sBuf[cur];

    // ---- QK^T partial over d-half: 16 MFMAs from LDS ----
    f4 s2[2];
    s2[0] = (f4){0.f, 0.f, 0.f, 0.f};
    s2[1] = (f4){0.f, 0.f, 0.f, 0.f};
#pragma unroll
    for (int ch = 0; ch < 8; ++ch) {
#pragma unroll
      for (int cc = 0; cc < 2; ++cc) {
        int key = cc * 16 + ll;
        int c = dh * 32 + ch * 4 + lg;
        bf8 kf = *(const bf8*)(sK + key * 512 + ((c ^ (key & 7)) << 3));
        s2[cc] = __builtin_amdgcn_mfma_f32_16x16x32_bf16(qf[ch], kf, s2[cc], 0, 0, 0);
      }
    }
    // publish partials (bf16x4)
#pragma unroll
    for (int cc = 0; cc < 2; ++cc) {
      US4 w;
#pragma unroll
      for (int r = 0; r < 4; ++r) w.s[r] = f2bf(s2[cc][r]);
      sSx[qg][dh][cc][slot] = w;
    }
    __syncthreads();  // barA: sBuf[cur] QK^T reads + sSx writes settled

    // issue full next-tile image prefetch into the other buffer
    // (covered by softmax + PV; drained at barB)
    if (t + 1 < NT) {
      const unsigned short* gKn = W + ((size_t)(bN + t + 1) << 15);
      unsigned short* nb = sBuf[cur ^ 1];
#pragma unroll
      for (int i = 0; i < 8; ++i) {
        int chunk = i * 8 + wave;
        gload_lds16(gKn + chunk * 512 + lane * 8, nb + chunk * 512);
      }
    }

    // ---- full-D sum (fixed order; identical in both dh waves) ----
    float e2[2][4];
#pragma unroll
    for (int cc = 0; cc < 2; ++cc) {
      US4 lo = sSx[qg][0][cc][slot];
      US4 hi = sSx[qg][1][cc][slot];
#pragma unroll
      for (int r = 0; r < 4; ++r)
        e2[cc][r] = (bf2f(lo.s[r]) + bf2f(hi.s[r])) * scale - bias[r];  // masked -> -1e9
    }

    // ---- online softmax (R19 verbatim; replicated across dh) ----
    float tm[4];
#pragma unroll
    for (int r = 0; r < 4; ++r) tm[r] = fmaxf(e2[0][r], e2[1][r]);
#pragma unroll
    for (int off = 1; off < 16; off <<= 1)
#pragma unroll
      for (int r = 0; r < 4; ++r) tm[r] = fmaxf(tm[r], __shfl_xor(tm[r], off));

    float mn[4];
    bool change = false;
#pragma unroll
    for (int r = 0; r < 4; ++r) { mn[r] = fmaxf(m[r], tm[r]); change = change || (mn[r] > m[r]); }
    if (__any(change)) {
#pragma unroll
      for (int r = 0; r < 4; ++r) {
        float al = __expf(m[r] - mn[r]);
        lsum[r] *= al;
        m[r] = mn[r];
#pragma unroll
        for (int ct = 0; ct < 16; ++ct) o[ct][r] *= al;
      }
    }

    float ts[4] = {0.f, 0.f, 0.f, 0.f};
    unsigned short pb[2][4];
#pragma unroll
    for (int cc = 0; cc < 2; ++cc)
#pragma unroll
      for (int r = 0; r < 4; ++r) {
        float p = __expf(e2[cc][r] - m[r]);
        ts[r] += p;
        pb[cc][r] = f2bf(p);
      }
#pragma unroll
    for (int off = 1; off < 16; off <<= 1)
#pragma unroll
      for (int r = 0; r < 4; ++r) ts[r] += __shfl_xor(ts[r], off);
#pragma unroll
    for (int r = 0; r < 4; ++r) lsum[r] += ts[r];

    // ---- shared P (both dh waves write identical bytes; same-wave read) ----
    unsigned short* Pw = sP[qg];
#pragma unroll
    for (int cc = 0; cc < 2; ++cc)
#pragma unroll
      for (int r = 0; r < 4; ++r)
        Pw[(lg * 4 + r) * PPS + cc * 16 + ll] = pb[cc][r];
    bf8 af = *(const bf8*)(Pw + ll * PPS + lg * 8);

    // ---- PV: this wave's d-half of V from LDS (conflict-free swizzle) ----
    const unsigned short* sV = sBuf[cur] + 16384;
#pragma unroll
    for (int g2 = 0; g2 < 8; ++g2) {
      bf8 va0, va1;
      {
        int d0 = dh * 256 + (g2 * 2) * 16 + ll;
        int d1 = dh * 256 + (g2 * 2 + 1) * 16 + ll;
        va0 = *(const bf8*)(sV + d0 * 32 + ((lg ^ ((d0 >> 1) & 3)) << 3));
        va1 = *(const bf8*)(sV + d1 * 32 + ((lg ^ ((d1 >> 1) & 3)) << 3));
      }
      o[g2 * 2]     = __builtin_amdgcn_mfma_f32_16x16x32_bf16(af, va0, o[g2 * 2], 0, 0, 0);
      o[g2 * 2 + 1] = __builtin_amdgcn_mfma_f32_16x16x32_bf16(af, va1, o[g2 * 2 + 1], 0, 0, 0);
    }
    __syncthreads();  // barB: prefetch drained; sBuf[cur]/sSx/sP reads settled
    cur ^= 1;
  }

  // ---- epilogue: normalize, store 16q x 256d ----
  float inv[4];
#pragma unroll
  for (int r = 0; r < 4; ++r) inv[r] = 1.0f / lsum[r];
#pragma unroll
  for (int ct = 0; ct < 16; ++ct)
#pragma unroll
    for (int r = 0; r < 4; ++r) {
      size_t row = (size_t)b * Nn + q0 + lg * 4 + r;
      out[row * Dd + dh * 256 + ct * 16 + ll] = o[ct][r] * inv[r];
    }
}

// ---------------------------------------------------------------------------
// Fallback (no usable ws): R10 structure, KV=64, in-kernel convert.
// ---------------------------------------------------------------------------
__global__ __launch_bounds__(256, 1)
void attn_fb(const float* __restrict__ Xf, const int* __restrict__ mask,
             float* __restrict__ out) {
  __shared__ unsigned short sKf[KVF * Dd];
  __shared__ unsigned short sVt[Dd * KVF];
  __shared__ unsigned short sPf[4][16 * PPF];

  const int tid  = threadIdx.x;
  const int wave = tid >> 6, lane = tid & 63;
  const int lg = lane >> 4, ll = lane & 15;
  const int b  = blockIdx.y;
  const int q0 = blockIdx.x * 64 + wave * 16;

  bf8 qf[16];
  {
    const size_t qoff = ((size_t)b * Nn + q0 + ll) * Dd;
#pragma unroll
    for (int ch = 0; ch < 16; ++ch) {
      int doff = ch * 32 + lg * 8;
      float4 a = *(const float4*)(Xf + qoff + doff);
      float4 c = *(const float4*)(Xf + qoff + doff + 4);
      bf8 tt;
      tt[0] = (short)f2bf(a.x); tt[1] = (short)f2bf(a.y);
      tt[2] = (short)f2bf(a.z); tt[3] = (short)f2bf(a.w);
      tt[4] = (short)f2bf(c.x); tt[5] = (short)f2bf(c.y);
      tt[6] = (short)f2bf(c.z); tt[7] = (short)f2bf(c.w);
      qf[ch] = tt;
    }
  }
  float bias[4];
#pragma unroll
  for (int r = 0; r < 4; ++r)
    bias[r] = (1.0f - (float)mask[b * Nn + q0 + lg * 4 + r]) * 1e9f;
  float m[4], lsum[4];
  f4 o[32];
#pragma unroll
  for (int r = 0; r < 4; ++r) { m[r] = -1e30f; lsum[r] = 0.0f; }
#pragma unroll
  for (int ct = 0; ct < 32; ++ct) o[ct] = (f4){0.f, 0.f, 0.f, 0.f};
  const float scale = 0.044194173824159216f;

  for (int t = 0; t < NTF; ++t) {
    __syncthreads();
    const size_t base = ((size_t)b * Nn + t * KVF) * Dd;
#pragma unroll
    for (int it = 0; it < 16; ++it) {
      int idx = it * 256 + tid;
      int key = idx >> 6, c = idx & 63;
      const float* sp = Xf + base + key * Dd + c * 8;
      float4 a = *(const float4*)(sp);
      float4 d2 = *(const float4*)(sp + 4);
      U8 v;
      v.s[0] = f2bf(a.x); v.s[1] = f2bf(a.y); v.s[2] = f2bf(a.z); v.s[3] = f2bf(a.w);
      v.s[4] = f2bf(d2.x); v.s[5] = f2bf(d2.y); v.s[6] = f2bf(d2.z); v.s[7] = f2bf(d2.w);
      *(U8*)(sKf + key * 512 + ((c ^ (key & 7)) << 3)) = v;
      int ko = key >> 3, k7 = key & 7;
#pragma unroll
      for (int j = 0; j < 8; ++j) {
        int dd = c * 8 + j;
        sVt[dd * 64 + ((ko ^ j ^ (c & 7)) << 3) + k7] = v.s[j];
      }
    }
    __syncthreads();

    f4 s[4];
#pragma unroll
    for (int cc = 0; cc < 4; ++cc) s[cc] = (f4){0.f, 0.f, 0.f, 0.f};
#pragma unroll
    for (int ch = 0; ch < 16; ++ch)
#pragma unroll
      for (int cc = 0; cc < 4; ++cc) {
        int key = cc * 16 + ll;
        bf8 kf = *(const bf8*)(sKf + key * 512 + (((ch * 4 + lg) ^ (key & 7)) << 3));
        s[cc] = __builtin_amdgcn_mfma_f32_16x16x32_bf16(qf[ch], kf, s[cc], 0, 0, 0);
      }

    float e[4][4];
#pragma unroll
    for (int cc = 0; cc < 4; ++cc)
#pragma unroll
      for (int r = 0; r < 4; ++r) e[cc][r] = s[cc][r] * scale - bias[r];
    float tm[4];
#pragma unroll
    for (int r = 0; r < 4; ++r)
      tm[r] = fmaxf(fmaxf(e[0][r], e[1][r]), fmaxf(e[2][r], e[3][r]));
#pragma unroll
    for (int off = 1; off < 16; off <<= 1)
#pragma unroll
      for (int r = 0; r < 4; ++r) tm[r] = fmaxf(tm[r], __shfl_xor(tm[r], off));
    float mn[4]; bool change = false;
#pragma unroll
    for (int r = 0; r < 4; ++r) { mn[r] = fmaxf(m[r], tm[r]); change = change || (mn[r] > m[r]); }
    if (__any(change)) {
#pragma unroll
      for (int r = 0; r < 4; ++r) {
        float al = __expf(m[r] - mn[r]);
        lsum[r] *= al; m[r] = mn[r];
#pragma unroll
        for (int ct = 0; ct < 32; ++ct) o[ct][r] *= al;
      }
    }
    float ts[4] = {0.f, 0.f, 0.f, 0.f};
    unsigned short pb[4][4];
#pragma unroll
    for (int cc = 0; cc < 4; ++cc)
#pragma unroll
      for (int r = 0; r < 4; ++r) {
        float p = __expf(e[cc][r] - m[r]);
        ts[r] += p; pb[cc][r] = f2bf(p);
      }
#pragma unroll
    for (int off = 1; off < 16; off <<= 1)
#pragma unroll
      for (int r = 0; r < 4; ++r) ts[r] += __shfl_xor(ts[r], off);
#pragma unroll
    for (int r = 0; r < 4; ++r) lsum[r] += ts[r];

    unsigned short* Pw = sPf[wave];
#pragma unroll
    for (int cc = 0; cc < 4; ++cc)
#pragma unroll
      for (int r = 0; r < 4; ++r)
        Pw[(lg * 4 + r) * PPF + cc * 16 + ll] = pb[cc][r];
#pragma unroll
    for (int kc = 0; kc < 2; ++kc) {
      bf8 af = *(const bf8*)(Pw + ll * PPF + kc * 32 + lg * 8);
#pragma unroll
      for (int ct = 0; ct < 32; ++ct) {
        int d = ct * 16 + ll;
        bf8 vf = *(const bf8*)(sVt + d * 64 + (((kc * 4 + lg) ^ (d & 7) ^ ((d >> 3) & 7)) << 3));
        o[ct] = __builtin_amdgcn_mfma_f32_16x16x32_bf16(af, vf, o[ct], 0, 0, 0);
      }
    }
  }
  float inv[4];
#pragma unroll
  for (int r = 0; r < 4; ++r) inv[r] = 1.0f / lsum[r];
#pragma unroll
  for (int ct = 0; ct < 32; ++ct)
#pragma unroll
    for (int r = 0; r < 4; ++r) {
      size_t row = (size_t)b * Nn + q0 + lg * 4 + r;
      out[row * Dd + ct * 16 + ll] = o[ct][r] * inv[r];
    }
}

extern "C" void kernel_launch(void* const* d_in, const int* in_sizes, int n_in,
                              void* d_out, int out_size, void* d_ws, size_t ws_size,
                              hipStream_t stream) {
  (void)in_sizes; (void)n_in; (void)out_size;
  const float* X  = (const float*)d_in[0];
  const int* mask = (const int*)d_in[1];
  float* out = (float*)d_out;

  const size_t szImg = (size_t)Bb * NT * 65536;  // 32 MiB of bf16 images
  if (ws_size >= szImg) {
    unsigned short* W = (unsigned short*)d_ws;
    build_images<<<dim3(NT, Bb), 256, 0, stream>>>(X, W);
    attn_db<<<256, 512, 0, stream>>>(W, mask, out);
  } else {
    attn_fb<<<dim3(Nn / 64, Bb), 256, 0, stream>>>(X, mask, out);
  }
}

// Round 23
// 153.808 us; speedup vs baseline: 2.1563x; 1.1629x over previous
//
#include <hip/hip_runtime.h>

#define Bb 8
#define Nn 2048
#define Dd 512

#define KV 32            // keys per tile/image
#define NT 64            // images per batch
#define SPS 40           // sP row stride (u16; 80B, 16B-aligned rows)

// fallback (no ws): R10 structure
#define KVF 64
#define NTF (Nn / KVF)
#define PPF 72

typedef __attribute__((ext_vector_type(8))) short bf8;
typedef __attribute__((ext_vector_type(4))) float f4;
typedef __attribute__((ext_vector_type(16))) float f16v;
struct __align__(16) U8 { unsigned short s[8]; };
struct __align__(8) US4 { unsigned short s[4]; };

__device__ __forceinline__ unsigned short f2bf(float f) {
  union { float f; unsigned u; } v; v.f = f;
  unsigned r = v.u + 0x7fffu + ((v.u >> 16) & 1u);
  return (unsigned short)(r >> 16);
}
__device__ __forceinline__ float bf2f(unsigned short h) {
  union { unsigned u; float f; } v; v.u = ((unsigned)h) << 16; return v.f;
}

// async global->LDS, 16B per lane; LDS dest = wave-uniform base + lane*16
__device__ __forceinline__ void gload_lds16(const unsigned short* g, unsigned short* l) {
  __builtin_amdgcn_global_load_lds(
      (const __attribute__((address_space(1))) void*)g,
      (__attribute__((address_space(3))) void*)l, 16, 0, 0);
}

// ---------------------------------------------------------------------------
// Build per-(b,tile) FRAGMENT-MAJOR images for the 32x32x16 MFMA path.
// Image = [K 32 frags | V 32 frags] x 1 KB = 64 KB per (b,tile).
// K frag f (0..31), lane L: element ( key = L&31, d = f*16 + (L>>5)*8 + e )
//   at u16 offset (f*64 + L)*8 + e  -> kf/qf reads are contiguous 1 KB bursts.
// V frag fv = dc*2+m (0..31), lane L: element ( d = dc*32 + (L&31),
//   key = m*16 + (L>>5)*8 + e ) at 16384 + (fv*64 + L)*8 + e.
// ---------------------------------------------------------------------------
__global__ __launch_bounds__(256)
void build_images(const float* __restrict__ X, unsigned short* __restrict__ W) {
  __shared__ float sT[KV * Dd];  // 64 KB
  const int t = blockIdx.x, b = blockIdx.y, tid = threadIdx.x;
  const float* src = X + ((size_t)b * Nn + t * KV) * Dd;
#pragma unroll
  for (int i = 0; i < 16; ++i) {
    int idx = i * 256 + tid;
    *(float4*)(sT + idx * 4) = *(const float4*)(src + idx * 4);
  }
  __syncthreads();
  unsigned short* img = W + ((size_t)(b * NT + t) << 15);
  // K frags
#pragma unroll
  for (int i = 0; i < 8; ++i) {
    int slot = i * 256 + tid;         // f*64 + L, 0..2047
    int f = slot >> 6, L = slot & 63;
    const float* p = sT + (L & 31) * Dd + f * 16 + (L >> 5) * 8;
    U8 v;
#pragma unroll
    for (int e = 0; e < 8; ++e) v.s[e] = f2bf(p[e]);
    *(U8*)(img + slot * 8) = v;
  }
  // V frags
#pragma unroll
  for (int i = 0; i < 8; ++i) {
    int slot = i * 256 + tid;
    int fv = slot >> 6, L = slot & 63;
    int dcol = (fv >> 1) * 32 + (L & 31);
    int k0 = (fv & 1) * 16 + (L >> 5) * 8;
    U8 v;
#pragma unroll
    for (int e = 0; e < 8; ++e) v.s[e] = f2bf(sT[(k0 + e) * Dd + dcol]);
    *(U8*)(img + 16384 + slot * 8) = v;
  }
}

// ---------------------------------------------------------------------------
// 32x32x16 attention. 512 thr = 8 waves = 2 qg x 4 dq. Block = 64 q-rows.
// Wave (qg,dq): QK^T partial S[32q x 32k] over d-quarter dq*128..+128
// (8 MFMAs, dual acc chain); partials exchanged via packed sSx; softmax is
// NO-max (p = exp(s*scale*mask); masked rows p=1 exact -> uniform collapse;
// scores bounded ~30 so f32-safe; numerics validated R20/21); row-sums via
// ones-MFMA into lacc whose reg<->row map matches o exactly (no cross-lane).
// PV: O[32q x 128d(dq)] via 8 MFMAs. All frag reads contiguous 1 KB bursts.
// Dbuf 64 KB images staged by global_load_lds; 2 barriers/tile; no setprio.
// Accumulators (o 64 + sa/sb 32 + lacc 16 = 112) live in AGPRs; ~95 VGPR.
// ---------------------------------------------------------------------------
__global__ __launch_bounds__(512, 1)
void attn32(const unsigned short* __restrict__ W, const int* __restrict__ mask,
            float* __restrict__ out) {
  __shared__ unsigned short sBuf[2][32768];      // 2 x 64 KB images
  __shared__ unsigned short sSx[2 * 16 * 64 * 4];  // [qg][i][lane][slice] 16 KB
  __shared__ unsigned short sP[2 * 32 * SPS];    // [qg][32 q][SPS] 5 KB

  const int tid  = threadIdx.x;
  const int wave = tid >> 6;
  const int qg = wave >> 2, dq = wave & 3;
  const int lane = tid & 63;
  const int l31 = lane & 31, h = lane >> 5;
  const int rowsh = h * 4;
  const int bid = blockIdx.x;
  const int b = bid & 7;                      // XCD-batch affinity
  const int qb = bid >> 3;                    // 0..31
  const int q0 = qb * 64;
  const int bN = b * NT;
  const float scale = 0.044194173824159216f;  // 1/sqrt(512)

  // Q fragments (A-layout row = l31, k = h*8+e per 16-d chunk) from Q-tile image
  bf8 qf[8];
  {
    const unsigned short* qimg = W + ((size_t)(bN + qb * 2 + qg) << 15);
#pragma unroll
    for (int g = 0; g < 8; ++g)
      qf[g] = *(const bf8*)(qimg + (dq * 8 + g) * 512 + lane * 8);
  }

  // mask bits for this qg's 32 rows -> per-reg row scale (0 or scale)
  float rs16[16];
  {
    int mv = mask[b * Nn + q0 + qg * 32 + l31];
    unsigned mb = (unsigned)(__ballot(mv != 0) & 0xffffffffull);
#pragma unroll
    for (int i = 0; i < 16; ++i) {
      int row = (i & 3) + 8 * (i >> 2) + rowsh;
      rs16[i] = ((mb >> row) & 1u) ? scale : 0.0f;
    }
  }

  bf8 ones;
#pragma unroll
  for (int i = 0; i < 8; ++i) ones[i] = (short)0x3F80;  // bf16 1.0

  f16v o0, o1, o2, o3, lacc;
#pragma unroll
  for (int i = 0; i < 16; ++i) { o0[i] = 0.f; o1[i] = 0.f; o2[i] = 0.f; o3[i] = 0.f; lacc[i] = 0.f; }

  // prologue: stage image of tile 0
  {
    const unsigned short* img0 = W + ((size_t)bN << 15);
#pragma unroll
    for (int i = 0; i < 8; ++i) {
      int chunk = i * 8 + wave;  // 0..63 x 1 KB
      gload_lds16(img0 + chunk * 512 + lane * 8, sBuf[0] + chunk * 512);
    }
  }
  __syncthreads();

  int cur = 0;
  for (int t = 0; t < NT; ++t) {
    const unsigned short* sK = sBuf[cur];

    // ---- QK^T partial: 8 MFMAs (dual chain), contiguous kf bursts ----
    f16v sa, sb;
#pragma unroll
    for (int i = 0; i < 16; ++i) { sa[i] = 0.f; sb[i] = 0.f; }
#pragma unroll
    for (int g2 = 0; g2 < 4; ++g2) {
      bf8 k0 = *(const bf8*)(sK + (dq * 8 + g2 * 2) * 512 + lane * 8);
      bf8 k1 = *(const bf8*)(sK + (dq * 8 + g2 * 2 + 1) * 512 + lane * 8);
      sa = __builtin_amdgcn_mfma_f32_32x32x16_bf16(qf[g2 * 2], k0, sa, 0, 0, 0);
      sb = __builtin_amdgcn_mfma_f32_32x32x16_bf16(qf[g2 * 2 + 1], k1, sb, 0, 0, 0);
    }
    // publish partials: u16 scatter stride 4 (2-way, free)
#pragma unroll
    for (int i = 0; i < 16; ++i)
      sSx[((qg * 16 + i) * 64 + lane) * 4 + dq] = f2bf(sa[i] + sb[i]);
    __syncthreads();  // barA: image reads done, partials visible

    // issue next image into the other buffer (drains at barB)
    if (t + 1 < NT) {
      const unsigned short* gKn = W + ((size_t)(bN + t + 1) << 15);
      unsigned short* nb = sBuf[cur ^ 1];
#pragma unroll
      for (int i = 0; i < 8; ++i) {
        int chunk = i * 8 + wave;
        gload_lds16(gKn + chunk * 512 + lane * 8, nb + chunk * 512);
      }
    }

    // ---- no-max softmax: e = (sum of 4 slices)*rs; p = exp(e) -> sP ----
    unsigned short* Pq = sP + qg * 32 * SPS;
#pragma unroll
    for (int i = 0; i < 16; ++i) {
      US4 v = *(const US4*)(&sSx[((qg * 16 + i) * 64 + lane) * 4]);  // b64
      float e = (bf2f(v.s[0]) + bf2f(v.s[1]) + bf2f(v.s[2]) + bf2f(v.s[3])) * rs16[i];
      int row = (i & 3) + 8 * (i >> 2) + rowsh;
      Pq[row * SPS + l31] = f2bf(__expf(e));
    }
    // af: A-layout (row q = l31, keys m*16 + h*8 + e); all writers identical
    bf8 af0 = *(const bf8*)(Pq + l31 * SPS + h * 8);
    bf8 af1 = *(const bf8*)(Pq + l31 * SPS + 16 + h * 8);

    // row-sums via ones-MFMA (reg<->row map identical to o)
    lacc = __builtin_amdgcn_mfma_f32_32x32x16_bf16(af0, ones, lacc, 0, 0, 0);
    lacc = __builtin_amdgcn_mfma_f32_32x32x16_bf16(af1, ones, lacc, 0, 0, 0);

    // ---- PV: this wave's d-quarter, 8 MFMAs, contiguous vf bursts ----
    const unsigned short* sV = sBuf[cur] + 16384;
    {
      bf8 v0 = *(const bf8*)(sV + ((dq * 4 + 0) * 2) * 512 + lane * 8);
      bf8 v1 = *(const bf8*)(sV + ((dq * 4 + 0) * 2 + 1) * 512 + lane * 8);
      o0 = __builtin_amdgcn_mfma_f32_32x32x16_bf16(af0, v0, o0, 0, 0, 0);
      o0 = __builtin_amdgcn_mfma_f32_32x32x16_bf16(af1, v1, o0, 0, 0, 0);
      v0 = *(const bf8*)(sV + ((dq * 4 + 1) * 2) * 512 + lane * 8);
      v1 = *(const bf8*)(sV + ((dq * 4 + 1) * 2 + 1) * 512 + lane * 8);
      o1 = __builtin_amdgcn_mfma_f32_32x32x16_bf16(af0, v0, o1, 0, 0, 0);
      o1 = __builtin_amdgcn_mfma_f32_32x32x16_bf16(af1, v1, o1, 0, 0, 0);
      v0 = *(const bf8*)(sV + ((dq * 4 + 2) * 2) * 512 + lane * 8);
      v1 = *(const bf8*)(sV + ((dq * 4 + 2) * 2 + 1) * 512 + lane * 8);
      o2 = __builtin_amdgcn_mfma_f32_32x32x16_bf16(af0, v0, o2, 0, 0, 0);
      o2 = __builtin_amdgcn_mfma_f32_32x32x16_bf16(af1, v1, o2, 0, 0, 0);
      v0 = *(const bf8*)(sV + ((dq * 4 + 3) * 2) * 512 + lane * 8);
      v1 = *(const bf8*)(sV + ((dq * 4 + 3) * 2 + 1) * 512 + lane * 8);
      o3 = __builtin_amdgcn_mfma_f32_32x32x16_bf16(af0, v0, o3, 0, 0, 0);
      o3 = __builtin_amdgcn_mfma_f32_32x32x16_bf16(af1, v1, o3, 0, 0, 0);
    }
    __syncthreads();  // barB: prefetch drained; sSx/sP/image reads settled
    cur ^= 1;
  }

  // ---- epilogue: normalize by lacc (same reg<->row map), store f32 ----
#pragma unroll
  for (int i = 0; i < 16; ++i) {
    int row = (i & 3) + 8 * (i >> 2) + rowsh;
    size_t gr = (size_t)b * Nn + q0 + qg * 32 + row;
    float inv = 1.0f / lacc[i];
    out[gr * Dd + dq * 128 + 0 * 32 + l31] = o0[i] * inv;
    out[gr * Dd + dq * 128 + 1 * 32 + l31] = o1[i] * inv;
    out[gr * Dd + dq * 128 + 2 * 32 + l31] = o2[i] * inv;
    out[gr * Dd + dq * 128 + 3 * 32 + l31] = o3[i] * inv;
  }
}

// ---------------------------------------------------------------------------
// Fallback (no usable ws): R10 structure, KV=64, in-kernel convert.
// ---------------------------------------------------------------------------
__global__ __launch_bounds__(256, 1)
void attn_fb(const float* __restrict__ Xf, const int* __restrict__ mask,
             float* __restrict__ out) {
  __shared__ unsigned short sKf[KVF * Dd];
  __shared__ unsigned short sVt[Dd * KVF];
  __shared__ unsigned short sPf[4][16 * PPF];

  const int tid  = threadIdx.x;
  const int wave = tid >> 6, lane = tid & 63;
  const int lg = lane >> 4, ll = lane & 15;
  const int b  = blockIdx.y;
  const int q0 = blockIdx.x * 64 + wave * 16;

  bf8 qf[16];
  {
    const size_t qoff = ((size_t)b * Nn + q0 + ll) * Dd;
#pragma unroll
    for (int ch = 0; ch < 16; ++ch) {
      int doff = ch * 32 + lg * 8;
      float4 a = *(const float4*)(Xf + qoff + doff);
      float4 c = *(const float4*)(Xf + qoff + doff + 4);
      bf8 tt;
      tt[0] = (short)f2bf(a.x); tt[1] = (short)f2bf(a.y);
      tt[2] = (short)f2bf(a.z); tt[3] = (short)f2bf(a.w);
      tt[4] = (short)f2bf(c.x); tt[5] = (short)f2bf(c.y);
      tt[6] = (short)f2bf(c.z); tt[7] = (short)f2bf(c.w);
      qf[ch] = tt;
    }
  }
  float bias[4];
#pragma unroll
  for (int r = 0; r < 4; ++r)
    bias[r] = (1.0f - (float)mask[b * Nn + q0 + lg * 4 + r]) * 1e9f;
  float m[4], lsum[4];
  f4 o[32];
#pragma unroll
  for (int r = 0; r < 4; ++r) { m[r] = -1e30f; lsum[r] = 0.0f; }
#pragma unroll
  for (int ct = 0; ct < 32; ++ct) o[ct] = (f4){0.f, 0.f, 0.f, 0.f};
  const float scale = 0.044194173824159216f;

  for (int t = 0; t < NTF; ++t) {
    __syncthreads();
    const size_t base = ((size_t)b * Nn + t * KVF) * Dd;
#pragma unroll
    for (int it = 0; it < 16; ++it) {
      int idx = it * 256 + tid;
      int key = idx >> 6, c = idx & 63;
      const float* sp = Xf + base + key * Dd + c * 8;
      float4 a = *(const float4*)(sp);
      float4 d2 = *(const float4*)(sp + 4);
      U8 v;
      v.s[0] = f2bf(a.x); v.s[1] = f2bf(a.y); v.s[2] = f2bf(a.z); v.s[3] = f2bf(a.w);
      v.s[4] = f2bf(d2.x); v.s[5] = f2bf(d2.y); v.s[6] = f2bf(d2.z); v.s[7] = f2bf(d2.w);
      *(U8*)(sKf + key * 512 + ((c ^ (key & 7)) << 3)) = v;
      int ko = key >> 3, k7 = key & 7;
#pragma unroll
      for (int j = 0; j < 8; ++j) {
        int dd = c * 8 + j;
        sVt[dd * 64 + ((ko ^ j ^ (c & 7)) << 3) + k7] = v.s[j];
      }
    }
    __syncthreads();

    f4 s[4];
#pragma unroll
    for (int cc = 0; cc < 4; ++cc) s[cc] = (f4){0.f, 0.f, 0.f, 0.f};
#pragma unroll
    for (int ch = 0; ch < 16; ++ch)
#pragma unroll
      for (int cc = 0; cc < 4; ++cc) {
        int key = cc * 16 + ll;
        bf8 kf = *(const bf8*)(sKf + key * 512 + (((ch * 4 + lg) ^ (key & 7)) << 3));
        s[cc] = __builtin_amdgcn_mfma_f32_16x16x32_bf16(qf[ch], kf, s[cc], 0, 0, 0);
      }

    float e[4][4];
#pragma unroll
    for (int cc = 0; cc < 4; ++cc)
#pragma unroll
      for (int r = 0; r < 4; ++r) e[cc][r] = s[cc][r] * scale - bias[r];
    float tm[4];
#pragma unroll
    for (int r = 0; r < 4; ++r)
      tm[r] = fmaxf(fmaxf(e[0][r], e[1][r]), fmaxf(e[2][r], e[3][r]));
#pragma unroll
    for (int off = 1; off < 16; off <<= 1)
#pragma unroll
      for (int r = 0; r < 4; ++r) tm[r] = fmaxf(tm[r], __shfl_xor(tm[r], off));
    float mn[4]; bool change = false;
#pragma unroll
    for (int r = 0; r < 4; ++r) { mn[r] = fmaxf(m[r], tm[r]); change = change || (mn[r] > m[r]); }
    if (__any(change)) {
#pragma unroll
      for (int r = 0; r < 4; ++r) {
        float al = __expf(m[r] - mn[r]);
        lsum[r] *= al; m[r] = mn[r];
#pragma unroll
        for (int ct = 0; ct < 32; ++ct) o[ct][r] *= al;
      }
    }
    float ts[4] = {0.f, 0.f, 0.f, 0.f};
    unsigned short pb[4][4];
#pragma unroll
    for (int cc = 0; cc < 4; ++cc)
#pragma unroll
      for (int r = 0; r < 4; ++r) {
        float p = __expf(e[cc][r] - m[r]);
        ts[r] += p; pb[cc][r] = f2bf(p);
      }
#pragma unroll
    for (int off = 1; off < 16; off <<= 1)
#pragma unroll
      for (int r = 0; r < 4; ++r) ts[r] += __shfl_xor(ts[r], off);
#pragma unroll
    for (int r = 0; r < 4; ++r) lsum[r] += ts[r];

    unsigned short* Pw = sPf[wave];
#pragma unroll
    for (int cc = 0; cc < 4; ++cc)
#pragma unroll
      for (int r = 0; r < 4; ++r)
        Pw[(lg * 4 + r) * PPF + cc * 16 + ll] = pb[cc][r];
#pragma unroll
    for (int kc = 0; kc < 2; ++kc) {
      bf8 af = *(const bf8*)(Pw + ll * PPF + kc * 32 + lg * 8);
#pragma unroll
      for (int ct = 0; ct < 32; ++ct) {
        int d = ct * 16 + ll;
        bf8 vf = *(const bf8*)(sVt + d * 64 + (((kc * 4 + lg) ^ (d & 7) ^ ((d >> 3) & 7)) << 3));
        o[ct] = __builtin_amdgcn_mfma_f32_16x16x32_bf16(af, vf, o[ct], 0, 0, 0);
      }
    }
  }
  float inv[4];
#pragma unroll
  for (int r = 0; r < 4; ++r) inv[r] = 1.0f / lsum[r];
#pragma unroll
  for (int ct = 0; ct < 32; ++ct)
#pragma unroll
    for (int r = 0; r < 4; ++r) {
      size_t row = (size_t)b * Nn + q0 + lg * 4 + r;
      out[row * Dd + ct * 16 + ll] = o[ct][r] * inv[r];
    }
}

extern "C" void kernel_launch(void* const* d_in, const int* in_sizes, int n_in,
                              void* d_out, int out_size, void* d_ws, size_t ws_size,
                              hipStream_t stream) {
  (void)in_sizes; (void)n_in; (void)out_size;
  const float* X  = (const float*)d_in[0];
  const int* mask = (const int*)d_in[1];
  float* out = (float*)d_out;

  const size_t szImg = (size_t)Bb * NT * 65536;  // 32 MiB of bf16 images
  if (ws_size >= szImg) {
    unsigned short* W = (unsigned short*)d_ws;
    build_images<<<dim3(NT, Bb), 256, 0, stream>>>(X, W);
    attn32<<<256, 512, 0, stream>>>(W, mask, out);
  } else {
    attn_fb<<<dim3(Nn / 64, Bb), 256, 0, stream>>>(X, mask, out);
  }
}